// Round 8
// baseline (2123.644 us; speedup 1.0000x reference)
//
#include <hip/hip_runtime.h>
#include <stdint.h>

#define Bsz 256
#define Ssz 512
#define Fsz 128
#define Hsz 128

// d_out float offsets (return order: h_enc, output, z, gamma, dis, dis_perm)
#define HOFF_OUT   32768
#define HOFF_Z     16809984
#define HOFF_G     16843008
#define HOFF_DIS   16844032
#define HOFF_DISP  17106176

typedef __attribute__((ext_vector_type(8))) short short8;
typedef __attribute__((ext_vector_type(4))) short short4_;
typedef __attribute__((ext_vector_type(4))) float f32x4;

__device__ __forceinline__ short f2bf(float f){
  uint32_t u = __float_as_uint(f);
  u += 0x7FFFu + ((u >> 16) & 1u);          // RNE
  return (short)(u >> 16);
}
__device__ __forceinline__ float bf2f(short h){
  return __uint_as_float(((uint32_t)(uint16_t)h) << 16);
}

__device__ __forceinline__ f32x4 MFMA(short8 a, short8 b, f32x4 c){
  f32x4 d;
  asm("v_mfma_f32_16x16x32_bf16 %0, %1, %2, %3" : "=v"(d) : "v"(a), "v"(b), "v"(c));
  return d;
}

__device__ __forceinline__ short8 ldcvt8(const float* p){
  float4 a = *(const float4*)p;
  float4 b = *(const float4*)(p + 4);
  short8 v;
  v[0]=f2bf(a.x); v[1]=f2bf(a.y); v[2]=f2bf(a.z); v[3]=f2bf(a.w);
  v[4]=f2bf(b.x); v[5]=f2bf(b.y); v[6]=f2bf(b.z); v[7]=f2bf(b.w);
  return v;
}
// split hi/lo bf16 (double-bf16 ~ 2^-18 relative)
__device__ __forceinline__ void ldcvt8_2(const float* p, short8& hi, short8& lo){
  #pragma unroll
  for (int q = 0; q < 8; ++q){
    float v = p[q];
    short h = f2bf(v);
    hi[q] = h;
    lo[q] = f2bf(v - bf2f(h));
  }
}

__device__ __forceinline__ float sigm(float x){ return 1.0f/(1.0f + __expf(-x)); }
__device__ __forceinline__ float tanh_(float x){
  x = fminf(15.0f, fmaxf(-15.0f, x));
  float e = __expf(2.0f*x);
  return (e - 1.0f)/(e + 1.0f);
}

// byte-swizzled LDS layout for bf16 tiles [16 rows][128 cols]: row stride 256B,
// element (row, col) at byte row*256 + ((2*col) ^ ((row&7)<<4))  -> conflict-free b128 frag reads
__device__ __forceinline__ int swzb(int row, int bo){ return row*256 + (bo ^ ((row & 7) << 4)); }
// fp32 h carry buffer swizzle (gate-phase scalar access)
#define H32IDX(row, j) ((row)*128 + ((j) ^ ((((row) >> 2) & 3) << 3)))

__device__ __forceinline__ short8 ldfrag(const short* buf, int l15, int lg, int kt){
  return *(const short8*)((const char*)buf + swzb(l15, (kt*32 + lg*8)*2));
}

__device__ __forceinline__ float rsum32(float v){
  v += __shfl_xor(v,1); v += __shfl_xor(v,2); v += __shfl_xor(v,4);
  v += __shfl_xor(v,8); v += __shfl_xor(v,16); return v;
}
__device__ __forceinline__ float rsum16(float v){
  v += __shfl_xor(v,1); v += __shfl_xor(v,2); v += __shfl_xor(v,4); v += __shfl_xor(v,8);
  return v;
}

// ---------------- Threefry-2x32 (JAX-exact) ----------------
__device__ __forceinline__ void tf2x32(uint32_t k0, uint32_t k1, uint32_t x0, uint32_t x1,
                                       uint32_t& o0, uint32_t& o1){
  const uint32_t ks2 = k0 ^ k1 ^ 0x1BD11BDAu;
  uint32_t a = x0 + k0, b = x1 + k1;
#define RR(r) { a += b; b = (b << r) | (b >> (32 - r)); b ^= a; }
  RR(13) RR(15) RR(26) RR(6)   a += k1;  b += ks2 + 1u;
  RR(17) RR(29) RR(16) RR(24)  a += ks2; b += k0 + 2u;
  RR(13) RR(15) RR(26) RR(6)   a += k0;  b += k1 + 3u;
  RR(17) RR(29) RR(16) RR(24)  a += k1;  b += ks2 + 4u;
  RR(13) RR(15) RR(26) RR(6)   a += ks2; b += k0 + 5u;
#undef RR
  o0 = a; o1 = b;
}

// jax.random.permutation(pk, 256) == _shuffle with
//   num_rounds = ceil(3*ln(256)/ln(2^32-1)) = 1   (denominator is ln(uint32max)!)
// One round, partitionable threefry (default since jax 0.4.36):
//   key, sub = split(pk):  sub = tf(pk, (0,1))
//   sort_keys = random_bits(sub, 32, (256,)):
//     bits1,bits2 = tf(sub, (0,i));  sort_keys[i] = (bits1 ^ bits2) >> (32-32)
//   _, x = lax.sort_key_val(sort_keys, arange(256))   [STABLE sort]
// Stable sort replicated exactly via rank sort on unique (key<<32)|position.
// perm[b*8+k] = jax.random.permutation(split(key(42),8)[k], 256)[b]
__global__ void perm_kernel(int* __restrict__ perm){
  const int k = blockIdx.x;
  const int tid = threadIdx.x;           // 256
  __shared__ unsigned long long ck[256];
  __shared__ int nv[256];
  uint32_t pk0, pk1, sub0, sub1, o0, o1;
  tf2x32(0u, 42u, 0u, (uint32_t)k, pk0, pk1);     // perm_keys[k] = tf(key42,(0,k))
  tf2x32(pk0, pk1, 0u, 1u, sub0, sub1);           // subkey (row 1 of split)
  tf2x32(sub0, sub1, 0u, (uint32_t)tid, o0, o1);  // bits1, bits2
  const uint32_t sk = o0 ^ o1;                    // partitionable 32-bit fold
  unsigned long long ci = (((unsigned long long)sk) << 32) | (unsigned)tid;
  ck[tid] = ci;
  __syncthreads();
  int rank = 0;
  #pragma unroll 8
  for (int jj = 0; jj < 256; ++jj) rank += (ck[jj] < ci) ? 1 : 0;
  nv[rank] = tid;
  __syncthreads();
  perm[tid*8 + k] = nv[tid];
}

// M = dec_Wih @ out_W (+ dec_Whh for rows<256, pre-summed r/z path); c = dec_Wih@out_b + dec_bih
__global__ void mprep(const float* __restrict__ dWih, const float* __restrict__ dWhh,
                      const float* __restrict__ oW, const float* __restrict__ oB,
                      const float* __restrict__ dBih,
                      float* __restrict__ M, float* __restrict__ c){
  const int r = blockIdx.x;    // 384
  const int kk = threadIdx.x;  // 128
  float acc = 0.f;
  for (int f = 0; f < 128; ++f) acc += dWih[r*128 + f] * oW[f*128 + kk];
  if (r < 256) acc += dWhh[r*128 + kk];
  M[r*128 + kk] = acc;
  if (kk == 0){
    float cc = dBih[r];
    for (int f = 0; f < 128; ++f) cc += dWih[r*128 + f] * oB[f];
    c[r] = cc;
  }
}

__global__ void gatherk(const float* __restrict__ out_dis, float* __restrict__ out_disp,
                        const int* __restrict__ perm){
  int idx = blockIdx.x*512 + threadIdx.x;          // 512*512 == 262144 exactly
  int jj = idx & 127, kk = (idx >> 7) & 7, b = idx >> 10;
  out_disp[idx] = out_dis[(perm[b*8 + kk]*8 + kk)*128 + jj];
}

__global__ __launch_bounds__(512, 2) void seqae_main(
    const float* __restrict__ x_in,
    const float* __restrict__ eWih, const float* __restrict__ eWhh,
    const float* __restrict__ eBih, const float* __restrict__ eBhh,
    const float* __restrict__ dWhh, const float* __restrict__ dBhh,
    const float* __restrict__ oW, const float* __restrict__ oB,
    const float* __restrict__ prot,
    const float* __restrict__ lnzW, const float* __restrict__ lnzB,
    const float* __restrict__ lnpW, const float* __restrict__ lnpB,
    const float* __restrict__ lnaW, const float* __restrict__ lnaB,
    const float* __restrict__ beta,
    const float* __restrict__ e1W, const float* __restrict__ e1B,
    const float* __restrict__ e2W, const float* __restrict__ e2B,
    const float* __restrict__ Mws, const float* __restrict__ cws,
    float* __restrict__ out)
{
  __shared__ short hbuf[2][2048];    // bf16 h (hi), swizzled, double-buffered
  __shared__ short hlob[2][2048];    // bf16 h (lo residual)
  __shared__ short xbuf[2][2048];    // bf16 x_t; epilogue: s_zln
  __shared__ float h32[2][2048];     // fp32 h carry; epilogue: s_pln/s_att/s_h1/red/s_na/s_rc
  __shared__ float henc[2048];

  const int tid = threadIdx.x;
  const int w = tid >> 6, lane = tid & 63;
  const int l15 = lane & 15, lg = lane >> 4;
  const int bbase = blockIdx.x * 16;
  const int jrow = w*16 + l15;             // gate/out column owned by this lane
  const int srow = tid >> 5, schunk = tid & 31;   // staging assignment
  const int j = jrow;

  // per-lane biases in registers
  const float be_r  = eBih[j]       + eBhh[j];
  const float be_z  = eBih[128 + j] + eBhh[128 + j];
  const float be_in = eBih[256 + j];
  const float be_hn = eBhh[256 + j];
  const float bd_r  = cws[j]        + dBhh[j];
  const float bd_z  = cws[128 + j]  + dBhh[128 + j];
  const float bd_in = cws[256 + j];
  const float bd_hn = dBhh[256 + j];
  const float b_o   = oB[j];

  for (int i = tid; i < 2048; i += 512){ h32[0][i] = 0.f; hbuf[0][i] = 0; hlob[0][i] = 0; }

  // encoder weight fragments: x-path single bf16; h-path split hi/lo
  short8 ex_r[4], ex_z[4], ex_i[4];
  short8 eh_rh[4], eh_rl[4], eh_zh[4], eh_zl[4], eh_nh[4], eh_nl[4];
  #pragma unroll
  for (int kt = 0; kt < 4; ++kt){
    const int off = kt*32 + lg*8;
    ex_r[kt] = ldcvt8(eWih + (      j)*128 + off);
    ex_z[kt] = ldcvt8(eWih + (128 + j)*128 + off);
    ex_i[kt] = ldcvt8(eWih + (256 + j)*128 + off);
    ldcvt8_2(eWhh + (      j)*128 + off, eh_rh[kt], eh_rl[kt]);
    ldcvt8_2(eWhh + (128 + j)*128 + off, eh_zh[kt], eh_zl[kt]);
    ldcvt8_2(eWhh + (256 + j)*128 + off, eh_nh[kt], eh_nl[kt]);
  }

  // stage x_0 (and accumulate ||a||^2)
  float na_reg = 0.f;
  {
    float4 xf = *(const float4*)(x_in + ((bbase + srow)*Ssz + 0)*Fsz + schunk*4);
    na_reg += xf.x*xf.x + xf.y*xf.y + xf.z*xf.z + xf.w*xf.w;
    short4_ s; s[0]=f2bf(xf.x); s[1]=f2bf(xf.y); s[2]=f2bf(xf.z); s[3]=f2bf(xf.w);
    *(short4_*)((char*)&xbuf[0][0] + swzb(srow, schunk*8)) = s;
  }
  __syncthreads();

  // -------- encoder: 512 steps --------
  for (int t = 0; t < Ssz; ++t){
    const int cur = t & 1, nxt = cur ^ 1;
    float4 xf;
    const bool hav = (t + 1 < Ssz);
    if (hav) xf = *(const float4*)(x_in + ((bbase + srow)*Ssz + (t+1))*Fsz + schunk*4);

    short8 axf[4], ahh[4], ahl[4];
    #pragma unroll
    for (int kt = 0; kt < 4; ++kt){
      axf[kt] = ldfrag(&xbuf[cur][0], l15, lg, kt);
      ahh[kt] = ldfrag(&hbuf[cur][0], l15, lg, kt);
      ahl[kt] = ldfrag(&hlob[cur][0], l15, lg, kt);
    }
    f32x4 ar = {0,0,0,0}, az = {0,0,0,0}, ai = {0,0,0,0}, an = {0,0,0,0};
    #pragma unroll
    for (int kt = 0; kt < 4; ++kt){
      ar = MFMA(axf[kt], ex_r[kt], ar);
      az = MFMA(axf[kt], ex_z[kt], az);
      ai = MFMA(axf[kt], ex_i[kt], ai);
      ar = MFMA(ahh[kt], eh_rh[kt], ar);
      ar = MFMA(ahl[kt], eh_rh[kt], ar);
      ar = MFMA(ahh[kt], eh_rl[kt], ar);
      az = MFMA(ahh[kt], eh_zh[kt], az);
      az = MFMA(ahl[kt], eh_zh[kt], az);
      az = MFMA(ahh[kt], eh_zl[kt], az);
      an = MFMA(ahh[kt], eh_nh[kt], an);
      an = MFMA(ahl[kt], eh_nh[kt], an);
      an = MFMA(ahh[kt], eh_nl[kt], an);
    }
    #pragma unroll
    for (int reg = 0; reg < 4; ++reg){
      const int row = lg*4 + reg;
      float r = sigm(ar[reg] + be_r);
      float z = sigm(az[reg] + be_z);
      float n = tanh_(ai[reg] + be_in + r*(an[reg] + be_hn));
      float hold = h32[cur][H32IDX(row, j)];
      float hv = n + z*(hold - n);
      h32[nxt][H32IDX(row, j)] = hv;
      short hh = f2bf(hv);
      short hl = f2bf(hv - bf2f(hh));
      *(short*)((char*)&hbuf[nxt][0] + swzb(row, 2*j)) = hh;
      *(short*)((char*)&hlob[nxt][0] + swzb(row, 2*j)) = hl;
    }
    if (hav){
      na_reg += xf.x*xf.x + xf.y*xf.y + xf.z*xf.z + xf.w*xf.w;
      short4_ s; s[0]=f2bf(xf.x); s[1]=f2bf(xf.y); s[2]=f2bf(xf.z); s[3]=f2bf(xf.w);
      *(short4_*)((char*)&xbuf[nxt][0] + swzb(srow, schunk*8)) = s;
    }
    __syncthreads();
  }

  // h_enc lives in buffer 0. Save it (LDS + global).
  for (int i2 = tid; i2 < 2048; i2 += 512){
    int row = i2 >> 7, jj = i2 & 127;
    float v = h32[0][H32IDX(row, jj)];
    henc[i2] = v;
    out[(bbase + row)*128 + jj] = v;
  }

  // decoder weight fragments, all split hi/lo (gi fused through M; r/z pre-summed with Whh)
  short8 d_oh[4], d_ol[4], d_rh[4], d_rl[4], d_zh[4], d_zl[4], d_ih[4], d_il[4], d_nh[4], d_nl[4];
  #pragma unroll
  for (int kt = 0; kt < 4; ++kt){
    const int off = kt*32 + lg*8;
    ldcvt8_2(oW   + (      j)*128 + off, d_oh[kt], d_ol[kt]);
    ldcvt8_2(Mws  + (      j)*128 + off, d_rh[kt], d_rl[kt]);
    ldcvt8_2(Mws  + (128 + j)*128 + off, d_zh[kt], d_zl[kt]);
    ldcvt8_2(Mws  + (256 + j)*128 + off, d_ih[kt], d_il[kt]);
    ldcvt8_2(dWhh + (256 + j)*128 + off, d_nh[kt], d_nl[kt]);
  }

  float dot_p[4] = {0,0,0,0}, nb_p[4] = {0,0,0,0};
  // -------- decoder: 512 steps (emits output at t = S-1-i) --------
  for (int i = 0; i < Ssz; ++i){
    const int cur = i & 1, nxt = cur ^ 1;
    const int tt = Ssz - 1 - i;
    float xv[4];
    #pragma unroll
    for (int reg = 0; reg < 4; ++reg){
      const int row = lg*4 + reg;
      xv[reg] = x_in[((bbase + row)*Ssz + tt)*Fsz + j];
    }
    short8 ahh[4], ahl[4];
    #pragma unroll
    for (int kt = 0; kt < 4; ++kt){
      ahh[kt] = ldfrag(&hbuf[cur][0], l15, lg, kt);
      ahl[kt] = ldfrag(&hlob[cur][0], l15, lg, kt);
    }
    f32x4 ao = {0,0,0,0}, ar = {0,0,0,0}, az = {0,0,0,0}, ai = {0,0,0,0}, an = {0,0,0,0};
    #pragma unroll
    for (int kt = 0; kt < 4; ++kt){
      ao = MFMA(ahh[kt], d_oh[kt], ao);
      ao = MFMA(ahl[kt], d_oh[kt], ao);
      ao = MFMA(ahh[kt], d_ol[kt], ao);
      ar = MFMA(ahh[kt], d_rh[kt], ar);
      ar = MFMA(ahl[kt], d_rh[kt], ar);
      ar = MFMA(ahh[kt], d_rl[kt], ar);
      az = MFMA(ahh[kt], d_zh[kt], az);
      az = MFMA(ahl[kt], d_zh[kt], az);
      az = MFMA(ahh[kt], d_zl[kt], az);
      ai = MFMA(ahh[kt], d_ih[kt], ai);
      ai = MFMA(ahl[kt], d_ih[kt], ai);
      ai = MFMA(ahh[kt], d_il[kt], ai);
      an = MFMA(ahh[kt], d_nh[kt], an);
      an = MFMA(ahl[kt], d_nh[kt], an);
      an = MFMA(ahh[kt], d_nl[kt], an);
    }
    #pragma unroll
    for (int reg = 0; reg < 4; ++reg){
      const int row = lg*4 + reg;
      float o = ao[reg] + b_o;
      float r = sigm(ar[reg] + bd_r);
      float z = sigm(az[reg] + bd_z);
      float n = tanh_(ai[reg] + bd_in + r*(an[reg] + bd_hn));
      float hold = h32[cur][H32IDX(row, j)];
      float hv = n + z*(hold - n);
      h32[nxt][H32IDX(row, j)] = hv;
      short hh = f2bf(hv);
      short hl = f2bf(hv - bf2f(hh));
      *(short*)((char*)&hbuf[nxt][0] + swzb(row, 2*j)) = hh;
      *(short*)((char*)&hlob[nxt][0] + swzb(row, 2*j)) = hl;
      out[HOFF_OUT + ((bbase + row)*Ssz + tt)*Fsz + j] = o;
      dot_p[reg] += xv[reg]*o;
      nb_p[reg]  += o*o;
    }
    __syncthreads();
  }

  // ---- epilogue LDS overlays (hbuf/hlob/xbuf/h32 are dead for their old roles) ----
  float (*s_zln)[128] = reinterpret_cast<float(*)[128]>(&xbuf[0][0]);   // 16x128
  float (*s_pln)[128] = reinterpret_cast<float(*)[128]>(&h32[0][0]);    // 8x128
  float (*s_att)[8]   = reinterpret_cast<float(*)[8]>(&h32[0][1024]);   // 16x8
  float (*s_h1)[10]   = reinterpret_cast<float(*)[10]>(&h32[0][1152]);  // 16x10
  float (*red)[8][16] = reinterpret_cast<float(*)[8][16]>(&h32[1][0]);  // 2x8x16
  float *s_na = &h32[1][256];
  float *s_rc = &h32[1][272];

  // rec_cosine partials
  {
    float v = rsum32(na_reg);
    if ((tid & 31) == 0) s_na[srow] = v;
  }
  #pragma unroll
  for (int reg = 0; reg < 4; ++reg){
    float d  = rsum16(dot_p[reg]);
    float nb = rsum16(nb_p[reg]);
    if (l15 == 0){ red[0][w][lg*4 + reg] = d; red[1][w][lg*4 + reg] = nb; }
  }
  __syncthreads();
  if (tid < 16){
    float d = 0.f, nb = 0.f;
    #pragma unroll
    for (int ww = 0; ww < 8; ++ww){ d += red[0][ww][tid]; nb += red[1][ww][tid]; }
    s_rc[tid] = d / (fmaxf(sqrtf(s_na[tid]), 1e-8f) * fmaxf(sqrtf(nb), 1e-8f));
  }

  // z_ln (16 rows x 32 threads)
  {
    const int rr = srow, tl = schunk;
    float xv4[4]; float sm = 0.f, sq = 0.f;
    #pragma unroll
    for (int q = 0; q < 4; ++q){ float v = henc[rr*128 + q*32 + tl]; xv4[q] = v; sm += v; sq += v*v; }
    sm = rsum32(sm); sq = rsum32(sq);
    float u = sm*(1.f/128.f), var = sq*(1.f/128.f) - u*u;
    float inv = rsqrtf(var + 1e-12f);
    #pragma unroll
    for (int q = 0; q < 4; ++q){ int jj = q*32 + tl; s_zln[rr][jj] = lnzW[jj]*(xv4[q]-u)*inv + lnzB[jj]; }
  }
  // prot_ln (8 rows x 32 threads)
  if (tid < 256){
    const int pr = tid >> 5, tl = tid & 31;
    float xv4[4]; float sm = 0.f, sq = 0.f;
    #pragma unroll
    for (int q = 0; q < 4; ++q){ float v = prot[pr*128 + q*32 + tl]; xv4[q] = v; sm += v; sq += v*v; }
    sm = rsum32(sm); sq = rsum32(sq);
    float u = sm*(1.f/128.f), var = sq*(1.f/128.f) - u*u;
    float inv = rsqrtf(var + 1e-12f);
    #pragma unroll
    for (int q = 0; q < 4; ++q){ int jj = q*32 + tl; s_pln[pr][jj] = lnpW[jj]*(xv4[q]-u)*inv + lnpB[jj]; }
  }
  __syncthreads();

  // attention logits + softmax over K=8
  {
    const int gid = tid >> 2, tq = tid & 3;      // 128 (row,k) groups x 4 threads
    const int rr2 = gid >> 3, kk = gid & 7;
    float p = 0.f;
    #pragma unroll 8
    for (int q = 0; q < 32; ++q){ int jj = tq + 4*q; p += s_zln[rr2][jj]*s_pln[kk][jj]; }
    p += __shfl_xor(p, 1); p += __shfl_xor(p, 2);
    if (tq == 0) s_att[rr2][kk] = p * 0.08838834764831845f;   // 1/sqrt(128)
  }
  __syncthreads();
  if (tid < 16){
    float mx = -1e30f;
    #pragma unroll
    for (int kk = 0; kk < 8; ++kk) mx = fmaxf(mx, s_att[tid][kk]);
    float sum = 0.f; float e[8];
    #pragma unroll
    for (int kk = 0; kk < 8; ++kk){ e[kk] = __expf(s_att[tid][kk] - mx); sum += e[kk]; }
    #pragma unroll
    for (int kk = 0; kk < 8; ++kk) s_att[tid][kk] = e[kk]/sum;
  }
  __syncthreads();

  // dis (+LN), dis.mean over K, z
  {
    const int rr = srow, tl = schunk;
    float dmq[4] = {0,0,0,0};
    for (int kk = 0; kk < 8; ++kk){
      float a = s_att[rr][kk];
      float vv[4]; float sm = 0.f, sq = 0.f;
      #pragma unroll
      for (int q = 0; q < 4; ++q){
        int jj = q*32 + tl;
        float v = beta[kk*128 + jj] + a*henc[rr*128 + jj];
        vv[q] = v; sm += v; sq += v*v;
      }
      sm = rsum32(sm); sq = rsum32(sq);
      float u = sm*(1.f/128.f), var = sq*(1.f/128.f) - u*u;
      float inv = rsqrtf(var + 1e-12f);
      #pragma unroll
      for (int q = 0; q < 4; ++q){
        int jj = q*32 + tl;
        float dv = lnaW[jj]*(vv[q]-u)*inv + lnaB[jj];
        out[HOFF_DIS + ((bbase + rr)*8 + kk)*128 + jj] = dv;
        dmq[q] += dv;
      }
    }
    #pragma unroll
    for (int q = 0; q < 4; ++q){
      int jj = q*32 + tl;
      float dm = dmq[q]*0.125f;
      out[HOFF_Z + (bbase + rr)*129 + jj] = dm;
      s_zln[rr][jj] = dm;                 // reuse as z storage
    }
    if (tl == 0) out[HOFF_Z + (bbase + rr)*129 + 128] = s_rc[rr];
  }
  __syncthreads();

  // estimator: h1 = tanh(z @ e1W.T + e1B)
  if (tid < 160){
    const int rr = tid/10, ii = tid%10;
    float acc = e1B[ii];
    const float* wrow = e1W + ii*129;
    for (int dd = 0; dd < 128; ++dd) acc += wrow[dd]*s_zln[rr][dd];
    acc += wrow[128]*s_rc[rr];
    s_h1[rr][ii] = tanh_(acc);
  }
  __syncthreads();
  // gamma = softmax(h1 @ e2W.T + e2B)
  if (tid < 16){
    float g[4]; float mx = -1e30f;
    #pragma unroll
    for (int ii = 0; ii < 4; ++ii){
      float a = e2B[ii];
      #pragma unroll
      for (int dd = 0; dd < 10; ++dd) a += e2W[ii*10 + dd]*s_h1[tid][dd];
      g[ii] = a; mx = fmaxf(mx, a);
    }
    float sum = 0.f;
    #pragma unroll
    for (int ii = 0; ii < 4; ++ii){ g[ii] = __expf(g[ii] - mx); sum += g[ii]; }
    #pragma unroll
    for (int ii = 0; ii < 4; ++ii) out[HOFF_G + (bbase + tid)*4 + ii] = g[ii]/sum;
  }
}

extern "C" void kernel_launch(void* const* d_in, const int* in_sizes, int n_in,
                              void* d_out, int out_size, void* d_ws, size_t ws_size,
                              hipStream_t stream){
  (void)in_sizes; (void)n_in; (void)out_size; (void)ws_size;
  const float* x    = (const float*)d_in[0];
  const float* eWih = (const float*)d_in[1];
  const float* eWhh = (const float*)d_in[2];
  const float* eBih = (const float*)d_in[3];
  const float* eBhh = (const float*)d_in[4];
  const float* dWih = (const float*)d_in[5];
  const float* dWhh = (const float*)d_in[6];
  const float* dBih = (const float*)d_in[7];
  const float* dBhh = (const float*)d_in[8];
  const float* oW   = (const float*)d_in[9];
  const float* oB   = (const float*)d_in[10];
  const float* prot = (const float*)d_in[11];
  const float* lnzW = (const float*)d_in[12];
  const float* lnzB = (const float*)d_in[13];
  const float* lnpW = (const float*)d_in[14];
  const float* lnpB = (const float*)d_in[15];
  const float* lnaW = (const float*)d_in[16];
  const float* lnaB = (const float*)d_in[17];
  const float* beta = (const float*)d_in[18];
  const float* e1W  = (const float*)d_in[19];
  const float* e1B  = (const float*)d_in[20];
  const float* e2W  = (const float*)d_in[21];
  const float* e2B  = (const float*)d_in[22];

  float* Mws = (float*)d_ws;
  float* cws = Mws + 384*128;
  int*  perm = (int*)(cws + 384);
  float* out = (float*)d_out;

  hipLaunchKernelGGL(mprep, dim3(384), dim3(128), 0, stream, dWih, dWhh, oW, oB, dBih, Mws, cws);
  hipLaunchKernelGGL(perm_kernel, dim3(8), dim3(256), 0, stream, perm);
  hipLaunchKernelGGL(seqae_main, dim3(16), dim3(512), 0, stream,
      x, eWih, eWhh, eBih, eBhh, dWhh, dBhh, oW, oB, prot,
      lnzW, lnzB, lnpW, lnpB, lnaW, lnaB, beta, e1W, e1B, e2W, e2B, Mws, cws, out);
  hipLaunchKernelGGL(gatherk, dim3(512), dim3(512), 0, stream, out + HOFF_DIS, out + HOFF_DISP, perm);
}

// Round 9
// 2025.405 us; speedup vs baseline: 1.0485x; 1.0485x over previous
//
#include <hip/hip_runtime.h>
#include <stdint.h>

#define Bsz 256
#define Ssz 512
#define Fsz 128
#define Hsz 128

// d_out float offsets (return order: h_enc, output, z, gamma, dis, dis_perm)
#define HOFF_OUT   32768
#define HOFF_Z     16809984
#define HOFF_G     16843008
#define HOFF_DIS   16844032
#define HOFF_DISP  17106176

typedef __attribute__((ext_vector_type(8))) short short8;
typedef __attribute__((ext_vector_type(4))) float f32x4;

__device__ __forceinline__ short f2bf(float f){
  uint32_t u = __float_as_uint(f);
  u += 0x7FFFu + ((u >> 16) & 1u);          // RNE
  return (short)(u >> 16);
}
__device__ __forceinline__ float bf2f(short h){
  return __uint_as_float(((uint32_t)(uint16_t)h) << 16);
}

__device__ __forceinline__ f32x4 MFMA(short8 a, short8 b, f32x4 c){
  f32x4 d;
  asm("v_mfma_f32_16x16x32_bf16 %0, %1, %2, %3" : "=v"(d) : "v"(a), "v"(b), "v"(c));
  return d;
}

__device__ __forceinline__ short8 ldcvt8(const float* p){
  short8 v;
  #pragma unroll
  for (int q = 0; q < 8; ++q) v[q] = f2bf(p[q]);
  return v;
}
__device__ __forceinline__ void ldcvt8_2(const float* p, short8& hi, short8& lo){
  #pragma unroll
  for (int q = 0; q < 8; ++q){
    float v = p[q];
    short h = f2bf(v);
    hi[q] = h;
    lo[q] = f2bf(v - bf2f(h));
  }
}

__device__ __forceinline__ float sigm(float x){ return 1.0f/(1.0f + __expf(-x)); }
__device__ __forceinline__ float tanh_(float x){
  x = fminf(15.0f, fmaxf(-15.0f, x));
  float e = __expf(2.0f*x);
  return (e - 1.0f)/(e + 1.0f);
}

// LDS-only barrier: do NOT drain vmcnt (global out-stores float free past it).
__device__ __forceinline__ void lbar(){
  asm volatile("s_waitcnt lgkmcnt(0)" ::: "memory");
  __builtin_amdgcn_s_barrier();
  asm volatile("" ::: "memory");
}

__device__ __forceinline__ float rsum32(float v){
  v += __shfl_xor(v,1); v += __shfl_xor(v,2); v += __shfl_xor(v,4);
  v += __shfl_xor(v,8); v += __shfl_xor(v,16); return v;
}
__device__ __forceinline__ float rsum16(float v){
  v += __shfl_xor(v,1); v += __shfl_xor(v,2); v += __shfl_xor(v,4); v += __shfl_xor(v,8);
  return v;
}

// ---------------- Threefry-2x32 (JAX-exact) ----------------
__device__ __forceinline__ void tf2x32(uint32_t k0, uint32_t k1, uint32_t x0, uint32_t x1,
                                       uint32_t& o0, uint32_t& o1){
  const uint32_t ks2 = k0 ^ k1 ^ 0x1BD11BDAu;
  uint32_t a = x0 + k0, b = x1 + k1;
#define RR(r) { a += b; b = (b << r) | (b >> (32 - r)); b ^= a; }
  RR(13) RR(15) RR(26) RR(6)   a += k1;  b += ks2 + 1u;
  RR(17) RR(29) RR(16) RR(24)  a += ks2; b += k0 + 2u;
  RR(13) RR(15) RR(26) RR(6)   a += k0;  b += k1 + 3u;
  RR(17) RR(29) RR(16) RR(24)  a += k1;  b += ks2 + 4u;
  RR(13) RR(15) RR(26) RR(6)   a += ks2; b += k0 + 5u;
#undef RR
  o0 = a; o1 = b;
}

// 1 round (num_rounds = ceil(3*ln(256)/ln(2^32-1)) = 1), partitionable threefry,
// sort key = bits1^bits2, stable sort via rank on (key<<32)|pos.  [verified R8]
__global__ void perm_kernel(int* __restrict__ perm){
  const int k = blockIdx.x;
  const int tid = threadIdx.x;           // 256
  __shared__ unsigned long long ck[256];
  __shared__ int nv[256];
  uint32_t pk0, pk1, sub0, sub1, o0, o1;
  tf2x32(0u, 42u, 0u, (uint32_t)k, pk0, pk1);
  tf2x32(pk0, pk1, 0u, 1u, sub0, sub1);
  tf2x32(sub0, sub1, 0u, (uint32_t)tid, o0, o1);
  const uint32_t sk = o0 ^ o1;
  unsigned long long ci = (((unsigned long long)sk) << 32) | (unsigned)tid;
  ck[tid] = ci;
  __syncthreads();
  int rank = 0;
  #pragma unroll 8
  for (int jj = 0; jj < 256; ++jj) rank += (ck[jj] < ci) ? 1 : 0;
  nv[rank] = tid;
  __syncthreads();
  perm[tid*8 + k] = nv[tid];
}

__global__ void mprep(const float* __restrict__ dWih, const float* __restrict__ dWhh,
                      const float* __restrict__ oW, const float* __restrict__ oB,
                      const float* __restrict__ dBih,
                      float* __restrict__ M, float* __restrict__ c){
  const int r = blockIdx.x;    // 384
  const int kk = threadIdx.x;  // 128
  float acc = 0.f;
  for (int f = 0; f < 128; ++f) acc += dWih[r*128 + f] * oW[f*128 + kk];
  if (r < 256) acc += dWhh[r*128 + kk];
  M[r*128 + kk] = acc;
  if (kk == 0){
    float cc = dBih[r];
    for (int f = 0; f < 128; ++f) cc += dWih[r*128 + f] * oB[f];
    c[r] = cc;
  }
}

__global__ void gatherk(const float* __restrict__ out_dis, float* __restrict__ out_disp,
                        const int* __restrict__ perm){
  int idx = blockIdx.x*512 + threadIdx.x;
  int jj = idx & 127, kk = (idx >> 7) & 7, b = idx >> 10;
  out_disp[idx] = out_dis[(perm[b*8 + kk]*8 + kk)*128 + jj];
}

#define FRAG(base, off) (*(const short8*)((const char*)(base) + (off)))

__global__ __launch_bounds__(512, 2) void seqae_main(
    const float* __restrict__ x_in,
    const float* __restrict__ eWih, const float* __restrict__ eWhh,
    const float* __restrict__ eBih, const float* __restrict__ eBhh,
    const float* __restrict__ dWhh, const float* __restrict__ dBhh,
    const float* __restrict__ oW, const float* __restrict__ oB,
    const float* __restrict__ prot,
    const float* __restrict__ lnzW, const float* __restrict__ lnzB,
    const float* __restrict__ lnpW, const float* __restrict__ lnpB,
    const float* __restrict__ lnaW, const float* __restrict__ lnaB,
    const float* __restrict__ beta,
    const float* __restrict__ e1W, const float* __restrict__ e1B,
    const float* __restrict__ e2W, const float* __restrict__ e2B,
    const float* __restrict__ Mws, const float* __restrict__ cws,
    float* __restrict__ out)
{
  __shared__ __align__(16) short hbuf[2][2048];   // bf16 h hi, swizzled, dbuf; epi: s_pln
  __shared__ __align__(16) short hlob[2][2048];   // bf16 h lo;                epi: red/s_na/s_rc/s_att/s_h1
  __shared__ __align__(16) short xbuf[2][2048];   // bf16 x_t;                 epi: s_zln
  __shared__ __align__(16) float henc[2048];

  const int tid = threadIdx.x;
  const int w = tid >> 6, lane = tid & 63;
  const int l15 = lane & 15, lg = lane >> 4;
  const int bbase = blockIdx.x * 16;
  const int j = w*16 + l15;                       // gate/out column owned by this lane
  const int srow = tid >> 5, schunk = tid & 31;   // staging assignment

  // per-lane biases in registers
  const float be_r  = eBih[j]       + eBhh[j];
  const float be_z  = eBih[128 + j] + eBhh[128 + j];
  const float be_in = eBih[256 + j];
  const float be_hn = eBhh[256 + j];
  const float bd_r  = cws[j]        + dBhh[j];
  const float bd_z  = cws[128 + j]  + dBhh[128 + j];
  const float bd_in = cws[256 + j];
  const float bd_hn = dBhh[256 + j];
  const float b_o   = oB[j];

  // precomputed per-lane LDS byte offsets (loop-invariant; parity via const array base)
  int fo[4];                                       // frag read offsets
  #pragma unroll
  for (int kt = 0; kt < 4; ++kt)
    fo[kt] = l15*256 + ((kt*64 + lg*16) ^ ((l15 & 7) << 4));
  int wo[4];                                       // h write offsets (per reg)
  #pragma unroll
  for (int reg = 0; reg < 4; ++reg){
    int row = lg*4 + reg;
    wo[reg] = row*256 + ((2*j) ^ ((row & 7) << 4));
  }
  const int xwo = srow*256 + ((schunk*8) ^ ((srow & 7) << 4));  // x stage offset

  for (int i = tid; i < 2048; i += 512){ hbuf[0][i] = 0; hlob[0][i] = 0; }
  float hold[4] = {0.f, 0.f, 0.f, 0.f};            // fp32 h carry — lane-local!

  // encoder weight fragments: x-path single bf16; h-path split hi/lo
  short8 ex_r[4], ex_z[4], ex_i[4];
  short8 eh_rh[4], eh_rl[4], eh_zh[4], eh_zl[4], eh_nh[4], eh_nl[4];
  #pragma unroll
  for (int kt = 0; kt < 4; ++kt){
    const int off = kt*32 + lg*8;
    ex_r[kt] = ldcvt8(eWih + (      j)*128 + off);
    ex_z[kt] = ldcvt8(eWih + (128 + j)*128 + off);
    ex_i[kt] = ldcvt8(eWih + (256 + j)*128 + off);
    ldcvt8_2(eWhh + (      j)*128 + off, eh_rh[kt], eh_rl[kt]);
    ldcvt8_2(eWhh + (128 + j)*128 + off, eh_zh[kt], eh_zl[kt]);
    ldcvt8_2(eWhh + (256 + j)*128 + off, eh_nh[kt], eh_nl[kt]);
  }

#define STORE_H(NXT, hv) do { \
    uint32_t pkh0, pkh1, pkl0, pkl1; \
    asm("v_cvt_pk_bf16_f32 %0, %1, %2" : "=v"(pkh0) : "v"(hv[0]), "v"(hv[1])); \
    asm("v_cvt_pk_bf16_f32 %0, %1, %2" : "=v"(pkh1) : "v"(hv[2]), "v"(hv[3])); \
    float l0 = hv[0] - __uint_as_float(pkh0 << 16); \
    float l1 = hv[1] - __uint_as_float(pkh0 & 0xffff0000u); \
    float l2 = hv[2] - __uint_as_float(pkh1 << 16); \
    float l3 = hv[3] - __uint_as_float(pkh1 & 0xffff0000u); \
    asm("v_cvt_pk_bf16_f32 %0, %1, %2" : "=v"(pkl0) : "v"(l0), "v"(l1)); \
    asm("v_cvt_pk_bf16_f32 %0, %1, %2" : "=v"(pkl1) : "v"(l2), "v"(l3)); \
    char* hbp = (char*)&hbuf[NXT][0]; char* lbp = (char*)&hlob[NXT][0]; \
    *(short*)(hbp + wo[0]) = (short)(pkh0); \
    *(short*)(hbp + wo[1]) = (short)(pkh0 >> 16); \
    *(short*)(hbp + wo[2]) = (short)(pkh1); \
    *(short*)(hbp + wo[3]) = (short)(pkh1 >> 16); \
    *(short*)(lbp + wo[0]) = (short)(pkl0); \
    *(short*)(lbp + wo[1]) = (short)(pkl0 >> 16); \
    *(short*)(lbp + wo[2]) = (short)(pkl1); \
    *(short*)(lbp + wo[3]) = (short)(pkl1 >> 16); \
  } while(0)

#define XSTAGE(NXT, xf) do { \
    na_reg += xf.x*xf.x + xf.y*xf.y + xf.z*xf.z + xf.w*xf.w; \
    uint32_t p0, p1; \
    asm("v_cvt_pk_bf16_f32 %0, %1, %2" : "=v"(p0) : "v"(xf.x), "v"(xf.y)); \
    asm("v_cvt_pk_bf16_f32 %0, %1, %2" : "=v"(p1) : "v"(xf.z), "v"(xf.w)); \
    *(uint64_t*)((char*)&xbuf[NXT][0] + xwo) = ((uint64_t)p1 << 32) | p0; \
  } while(0)

#define ENC_STEP(CUR) do { \
    short8 axf[4], ahh[4], ahl[4]; \
    _Pragma("unroll") \
    for (int kt = 0; kt < 4; ++kt){ \
      axf[kt] = FRAG(&xbuf[CUR][0], fo[kt]); \
      ahh[kt] = FRAG(&hbuf[CUR][0], fo[kt]); \
      ahl[kt] = FRAG(&hlob[CUR][0], fo[kt]); \
    } \
    f32x4 arA={0,0,0,0}, arB={0,0,0,0}, azA={0,0,0,0}, azB={0,0,0,0}; \
    f32x4 anA={0,0,0,0}, anB={0,0,0,0}, ai4={0,0,0,0}; \
    _Pragma("unroll") \
    for (int kt = 0; kt < 4; ++kt){ \
      arA = MFMA(axf[kt], ex_r[kt], arA); \
      azA = MFMA(axf[kt], ex_z[kt], azA); \
      anA = MFMA(ahh[kt], eh_nh[kt], anA); \
      ai4 = MFMA(axf[kt], ex_i[kt], ai4); \
      arB = MFMA(ahh[kt], eh_rh[kt], arB); \
      azB = MFMA(ahh[kt], eh_zh[kt], azB); \
      anB = MFMA(ahl[kt], eh_nh[kt], anB); \
      arA = MFMA(ahl[kt], eh_rh[kt], arA); \
      azA = MFMA(ahl[kt], eh_zh[kt], azA); \
      anA = MFMA(ahh[kt], eh_nl[kt], anA); \
      arB = MFMA(ahh[kt], eh_rl[kt], arB); \
      azB = MFMA(ahh[kt], eh_zl[kt], azB); \
    } \
    f32x4 arS = arA + arB, azS = azA + azB, anS = anA + anB; \
    float hv[4]; \
    _Pragma("unroll") \
    for (int reg = 0; reg < 4; ++reg){ \
      float r = sigm(arS[reg] + be_r); \
      float z = sigm(azS[reg] + be_z); \
      float n = tanh_(ai4[reg] + be_in + r*(anS[reg] + be_hn)); \
      float h2 = n + z*(hold[reg] - n); \
      hold[reg] = h2; hv[reg] = h2; \
    } \
    STORE_H(CUR ^ 1, hv); \
  } while(0)

  // stage x_0 (+ ||a||^2 partial)
  float na_reg = 0.f;
  const int xoff_lane = ((bbase + srow)*Ssz)*Fsz + schunk*4;   // per-lane, t-invariant
  {
    float4 xf = *(const float4*)(x_in + xoff_lane);
    XSTAGE(0, xf);
  }
  __syncthreads();

  // -------- encoder: 512 steps, unrolled x2 --------
  for (int t = 0; t < Ssz; t += 2){
    float4 xf1 = *(const float4*)(x_in + xoff_lane + (t+1)*Fsz);
    ENC_STEP(0);
    XSTAGE(1, xf1);
    lbar();
    const bool hav2 = (t + 2 < Ssz);
    float4 xf2;
    if (hav2) xf2 = *(const float4*)(x_in + xoff_lane + (t+2)*Fsz);
    ENC_STEP(1);
    if (hav2) XSTAGE(0, xf2);
    lbar();
  }

  // h_enc == hold regs (and hbuf/hlob[0]). Save to henc LDS + global.
  #pragma unroll
  for (int reg = 0; reg < 4; ++reg){
    int row = lg*4 + reg;
    henc[row*128 + j] = hold[reg];
    out[(bbase + row)*128 + j] = hold[reg];
  }

  // decoder weight fragments (gi fused through M; r/z pre-summed with Whh; o single-bf16+lo-on-hh)
  short8 d_oh[4], d_ol[4], d_rh[4], d_rl[4], d_zh[4], d_zl[4], d_ih[4], d_il[4], d_nh[4], d_nl[4];
  #pragma unroll
  for (int kt = 0; kt < 4; ++kt){
    const int off = kt*32 + lg*8;
    ldcvt8_2(oW   + (      j)*128 + off, d_oh[kt], d_ol[kt]);
    ldcvt8_2(Mws  + (      j)*128 + off, d_rh[kt], d_rl[kt]);
    ldcvt8_2(Mws  + (128 + j)*128 + off, d_zh[kt], d_zl[kt]);
    ldcvt8_2(Mws  + (256 + j)*128 + off, d_ih[kt], d_il[kt]);
    ldcvt8_2(dWhh + (256 + j)*128 + off, d_nh[kt], d_nl[kt]);
  }
  (void)d_ol;  // lo-terms of o dropped (non-recurrent; err ~1e-3 << threshold)

  int doff[4];   // per-reg element offset into [B,S,F] tensors (t-part excluded)
  #pragma unroll
  for (int reg = 0; reg < 4; ++reg){
    int row = lg*4 + reg;
    doff[reg] = (bbase + row)*Ssz*Fsz + j;
  }

  float dot_p[4] = {0,0,0,0}, nb_p[4] = {0,0,0,0};

#define DEC_STEP(CUR, TT) do { \
    const float* xt = x_in + (size_t)(TT)*Fsz; \
    float* ot = out + HOFF_OUT + (size_t)(TT)*Fsz; \
    float xv[4]; \
    _Pragma("unroll") \
    for (int reg = 0; reg < 4; ++reg) xv[reg] = xt[doff[reg]]; \
    short8 ahh[4], ahl[4]; \
    _Pragma("unroll") \
    for (int kt = 0; kt < 4; ++kt){ \
      ahh[kt] = FRAG(&hbuf[CUR][0], fo[kt]); \
      ahl[kt] = FRAG(&hlob[CUR][0], fo[kt]); \
    } \
    f32x4 ao4={0,0,0,0}, arA={0,0,0,0}, arB={0,0,0,0}, azA={0,0,0,0}, azB={0,0,0,0}; \
    f32x4 aiA={0,0,0,0}, aiB={0,0,0,0}, anA={0,0,0,0}, anB={0,0,0,0}; \
    _Pragma("unroll") \
    for (int kt = 0; kt < 4; ++kt){ \
      ao4 = MFMA(ahh[kt], d_oh[kt], ao4); \
      arA = MFMA(ahh[kt], d_rh[kt], arA); \
      azA = MFMA(ahh[kt], d_zh[kt], azA); \
      aiA = MFMA(ahh[kt], d_ih[kt], aiA); \
      anA = MFMA(ahh[kt], d_nh[kt], anA); \
      arB = MFMA(ahl[kt], d_rh[kt], arB); \
      azB = MFMA(ahl[kt], d_zh[kt], azB); \
      aiB = MFMA(ahl[kt], d_ih[kt], aiB); \
      anB = MFMA(ahl[kt], d_nh[kt], anB); \
      arB = MFMA(ahh[kt], d_rl[kt], arB); \
      azB = MFMA(ahh[kt], d_zl[kt], azB); \
      aiB = MFMA(ahh[kt], d_il[kt], aiB); \
      anB = MFMA(ahh[kt], d_nl[kt], anB); \
    } \
    f32x4 arS = arA + arB, azS = azA + azB, aiS = aiA + aiB, anS = anA + anB; \
    float hv[4], ov[4]; \
    _Pragma("unroll") \
    for (int reg = 0; reg < 4; ++reg){ \
      float o = ao4[reg] + b_o; \
      float r = sigm(arS[reg] + bd_r); \
      float z = sigm(azS[reg] + bd_z); \
      float n = tanh_(aiS[reg] + bd_in + r*(anS[reg] + bd_hn)); \
      float h2 = n + z*(hold[reg] - n); \
      hold[reg] = h2; hv[reg] = h2; ov[reg] = o; \
    } \
    STORE_H(CUR ^ 1, hv); \
    _Pragma("unroll") \
    for (int reg = 0; reg < 4; ++reg){ \
      ot[doff[reg]] = ov[reg]; \
      dot_p[reg] += xv[reg]*ov[reg]; \
      nb_p[reg]  += ov[reg]*ov[reg]; \
    } \
    lbar(); \
  } while(0)

  // -------- decoder: 512 steps (emits output at t = S-1-i), unrolled x2 --------
  for (int i = 0; i < Ssz; i += 2){
    const int tt = Ssz - 1 - i;
    DEC_STEP(0, tt);
    DEC_STEP(1, tt - 1);
  }

  // ---- epilogue LDS overlays ----
  float (*s_zln)[128] = reinterpret_cast<float(*)[128]>(&xbuf[0][0]);   // 16x128
  float (*s_pln)[128] = reinterpret_cast<float(*)[128]>(&hbuf[0][0]);   // 8x128
  float* lf = reinterpret_cast<float*>(&hlob[0][0]);
  float (*red)[8][16] = reinterpret_cast<float(*)[8][16]>(lf);          // 2x8x16
  float* s_na = lf + 256;
  float* s_rc = lf + 272;
  float (*s_att)[8]   = reinterpret_cast<float(*)[8]>(lf + 288);        // 16x8
  float (*s_h1)[10]   = reinterpret_cast<float(*)[10]>(lf + 416);       // 16x10

  // rec_cosine partials
  {
    float v = rsum32(na_reg);
    if ((tid & 31) == 0) s_na[srow] = v;
  }
  #pragma unroll
  for (int reg = 0; reg < 4; ++reg){
    float d  = rsum16(dot_p[reg]);
    float nb = rsum16(nb_p[reg]);
    if (l15 == 0){ red[0][w][lg*4 + reg] = d; red[1][w][lg*4 + reg] = nb; }
  }
  __syncthreads();
  if (tid < 16){
    float d = 0.f, nb = 0.f;
    #pragma unroll
    for (int ww = 0; ww < 8; ++ww){ d += red[0][ww][tid]; nb += red[1][ww][tid]; }
    s_rc[tid] = d / (fmaxf(sqrtf(s_na[tid]), 1e-8f) * fmaxf(sqrtf(nb), 1e-8f));
  }

  // z_ln (16 rows x 32 threads)
  {
    const int rr = srow, tl = schunk;
    float xv4[4]; float sm = 0.f, sq = 0.f;
    #pragma unroll
    for (int q = 0; q < 4; ++q){ float v = henc[rr*128 + q*32 + tl]; xv4[q] = v; sm += v; sq += v*v; }
    sm = rsum32(sm); sq = rsum32(sq);
    float u = sm*(1.f/128.f), var = sq*(1.f/128.f) - u*u;
    float inv = rsqrtf(var + 1e-12f);
    #pragma unroll
    for (int q = 0; q < 4; ++q){ int jj = q*32 + tl; s_zln[rr][jj] = lnzW[jj]*(xv4[q]-u)*inv + lnzB[jj]; }
  }
  // prot_ln (8 rows x 32 threads)
  if (tid < 256){
    const int pr = tid >> 5, tl = tid & 31;
    float xv4[4]; float sm = 0.f, sq = 0.f;
    #pragma unroll
    for (int q = 0; q < 4; ++q){ float v = prot[pr*128 + q*32 + tl]; xv4[q] = v; sm += v; sq += v*v; }
    sm = rsum32(sm); sq = rsum32(sq);
    float u = sm*(1.f/128.f), var = sq*(1.f/128.f) - u*u;
    float inv = rsqrtf(var + 1e-12f);
    #pragma unroll
    for (int q = 0; q < 4; ++q){ int jj = q*32 + tl; s_pln[pr][jj] = lnpW[jj]*(xv4[q]-u)*inv + lnpB[jj]; }
  }
  __syncthreads();

  // attention logits + softmax over K=8
  {
    const int gid = tid >> 2, tq = tid & 3;
    const int rr2 = gid >> 3, kk = gid & 7;
    float p = 0.f;
    #pragma unroll 8
    for (int q = 0; q < 32; ++q){ int jj = tq + 4*q; p += s_zln[rr2][jj]*s_pln[kk][jj]; }
    p += __shfl_xor(p, 1); p += __shfl_xor(p, 2);
    if (tq == 0) s_att[rr2][kk] = p * 0.08838834764831845f;   // 1/sqrt(128)
  }
  __syncthreads();
  if (tid < 16){
    float mx = -1e30f;
    #pragma unroll
    for (int kk = 0; kk < 8; ++kk) mx = fmaxf(mx, s_att[tid][kk]);
    float sum = 0.f; float e[8];
    #pragma unroll
    for (int kk = 0; kk < 8; ++kk){ e[kk] = __expf(s_att[tid][kk] - mx); sum += e[kk]; }
    #pragma unroll
    for (int kk = 0; kk < 8; ++kk) s_att[tid][kk] = e[kk]/sum;
  }
  __syncthreads();

  // dis (+LN), dis.mean over K, z
  {
    const int rr = srow, tl = schunk;
    float dmq[4] = {0,0,0,0};
    for (int kk = 0; kk < 8; ++kk){
      float a = s_att[rr][kk];
      float vv[4]; float sm = 0.f, sq = 0.f;
      #pragma unroll
      for (int q = 0; q < 4; ++q){
        int jj = q*32 + tl;
        float v = beta[kk*128 + jj] + a*henc[rr*128 + jj];
        vv[q] = v; sm += v; sq += v*v;
      }
      sm = rsum32(sm); sq = rsum32(sq);
      float u = sm*(1.f/128.f), var = sq*(1.f/128.f) - u*u;
      float inv = rsqrtf(var + 1e-12f);
      #pragma unroll
      for (int q = 0; q < 4; ++q){
        int jj = q*32 + tl;
        float dv = lnaW[jj]*(vv[q]-u)*inv + lnaB[jj];
        out[HOFF_DIS + ((bbase + rr)*8 + kk)*128 + jj] = dv;
        dmq[q] += dv;
      }
    }
    #pragma unroll
    for (int q = 0; q < 4; ++q){
      int jj = q*32 + tl;
      float dm = dmq[q]*0.125f;
      out[HOFF_Z + (bbase + rr)*129 + jj] = dm;
      s_zln[rr][jj] = dm;                 // reuse as z storage
    }
    if (tl == 0) out[HOFF_Z + (bbase + rr)*129 + 128] = s_rc[rr];
  }
  __syncthreads();

  // estimator: h1 = tanh(z @ e1W.T + e1B)
  if (tid < 160){
    const int rr = tid/10, ii = tid%10;
    float acc = e1B[ii];
    const float* wrow = e1W + ii*129;
    for (int dd = 0; dd < 128; ++dd) acc += wrow[dd]*s_zln[rr][dd];
    acc += wrow[128]*s_rc[rr];
    s_h1[rr][ii] = tanh_(acc);
  }
  __syncthreads();
  // gamma = softmax(h1 @ e2W.T + e2B)
  if (tid < 16){
    float g[4]; float mx = -1e30f;
    #pragma unroll
    for (int ii = 0; ii < 4; ++ii){
      float a = e2B[ii];
      #pragma unroll
      for (int dd = 0; dd < 10; ++dd) a += e2W[ii*10 + dd]*s_h1[tid][dd];
      g[ii] = a; mx = fmaxf(mx, a);
    }
    float sum = 0.f;
    #pragma unroll
    for (int ii = 0; ii < 4; ++ii){ g[ii] = __expf(g[ii] - mx); sum += g[ii]; }
    #pragma unroll
    for (int ii = 0; ii < 4; ++ii) out[HOFF_G + (bbase + tid)*4 + ii] = g[ii]/sum;
  }
}

extern "C" void kernel_launch(void* const* d_in, const int* in_sizes, int n_in,
                              void* d_out, int out_size, void* d_ws, size_t ws_size,
                              hipStream_t stream){
  (void)in_sizes; (void)n_in; (void)out_size; (void)ws_size;
  const float* x    = (const float*)d_in[0];
  const float* eWih = (const float*)d_in[1];
  const float* eWhh = (const float*)d_in[2];
  const float* eBih = (const float*)d_in[3];
  const float* eBhh = (const float*)d_in[4];
  const float* dWih = (const float*)d_in[5];
  const float* dWhh = (const float*)d_in[6];
  const float* dBih = (const float*)d_in[7];
  const float* dBhh = (const float*)d_in[8];
  const float* oW   = (const float*)d_in[9];
  const float* oB   = (const float*)d_in[10];
  const float* prot = (const float*)d_in[11];
  const float* lnzW = (const float*)d_in[12];
  const float* lnzB = (const float*)d_in[13];
  const float* lnpW = (const float*)d_in[14];
  const float* lnpB = (const float*)d_in[15];
  const float* lnaW = (const float*)d_in[16];
  const float* lnaB = (const float*)d_in[17];
  const float* beta = (const float*)d_in[18];
  const float* e1W  = (const float*)d_in[19];
  const float* e1B  = (const float*)d_in[20];
  const float* e2W  = (const float*)d_in[21];
  const float* e2B  = (const float*)d_in[22];

  float* Mws = (float*)d_ws;
  float* cws = Mws + 384*128;
  int*  perm = (int*)(cws + 384);
  float* out = (float*)d_out;

  hipLaunchKernelGGL(mprep, dim3(384), dim3(128), 0, stream, dWih, dWhh, oW, oB, dBih, Mws, cws);
  hipLaunchKernelGGL(perm_kernel, dim3(8), dim3(256), 0, stream, perm);
  hipLaunchKernelGGL(seqae_main, dim3(16), dim3(512), 0, stream,
      x, eWih, eWhh, eBih, eBhh, dWhh, dBhh, oW, oB, prot,
      lnzW, lnzB, lnpW, lnpB, lnaW, lnaB, beta, e1W, e1B, e2W, e2B, Mws, cws, out);
  hipLaunchKernelGGL(gatherk, dim3(512), dim3(512), 0, stream, out + HOFF_DIS, out + HOFF_DISP, perm);
}